// Round 12
// baseline (251.485 us; speedup 1.0000x reference)
//
#include <hip/hip_runtime.h>
#include <cstdint>

// B=4096, T=512, I=3, H=32, C=3
#define B_TOT 4096
#define T_LEN 512
#define CHUNK 128
#define LOG2E 1.44269504088896340736f

typedef _Float16 f16x8 __attribute__((ext_vector_type(8)));
typedef float    f32x4 __attribute__((ext_vector_type(4)));

__device__ __forceinline__ float ex2(float v)  { return __builtin_amdgcn_exp2f(v); }
__device__ __forceinline__ float rcp_(float v) { return __builtin_amdgcn_rcpf(v); }

// R12: barrier-free, issue-lean. 1024 single-wave blocks (1 wave/SIMD exact),
// 4 batches per wave, 2 states per lane. The wave computes ALL 32 hids of its
// 4 batches -> h round-trips through LDS within the wave: ds_write then
// ds_read in program order on the in-order DS pipe (lgkmcnt only, NO barrier,
// single h buffer: each step reads h(t) before writing h(t+1)).
// Recurrent matvec: 8x mfma_f32_16x16x32_f16 sharing one B fragment
// (B[k][col] = h[batch col&3][hid k]; cols duplicate the 4 batches x4).
//   MFMA g rows m: gate = m&3, hid = 4g + (m>>2)
//   => lane (n,kq) reg-quad of MFMA g = (i,f,g,o) of (batch n&3, hid 4g+kq).
// Lane states: s0 = (n&3, 4*(n>>2)+kq) from MFMA n>>2; s1 = same +16 from
// MFMA 4+(n>>2). Two 1-of-4 selects (24 cndmask). x+bias via 24 VALU fmaf
// (weights pre-scaled), x staged per-chunk in LDS, prefetched 1 step ahead.
// exp2 scales folded into all weights (sigmoid * -log2e, tanh(g) * -2log2e).
// Merged-reciprocal gate math: 5 exp2 + 2 rcp per state per step.
__global__ __launch_bounds__(64, 1)
void lstm_sw(const float* __restrict__ x,
             const float* __restrict__ W_ih,
             const float* __restrict__ W_hh,
             const float* __restrict__ b_ih,
             const float* __restrict__ b_hh,
             const float* __restrict__ W_fc,
             const float* __restrict__ b_fc,
             float* __restrict__ out)
{
    __shared__ __align__(16) _Float16 hbuf[4][40];        // 320 B, single buffer
    __shared__ __align__(16) float    xbuf[4][CHUNK][4];  // 8 KB, [batch][t][comp pad4]

    const int lane = threadIdx.x;     // single wave
    const int n    = lane & 15;
    const int kq   = lane >> 4;
    const int nb   = n & 3;           // my batch column
    const int g0   = n >> 2;          // my MFMA-group (0..3)
    const int tb   = blockIdx.x * 4;

    // ---- A fragments for the 8 gate-MFMAs (row m = n) ----
    const float sm = ((n & 3) == 2) ? (-2.0f * LOG2E) : (-LOG2E);
    f16x8 aW[8];
#pragma unroll
    for (int g = 0; g < 8; ++g) {
        const int R = (n & 3) * 32 + 4 * g + (n >> 2);   // gate=(n&3), hid=4g+(n>>2)
#pragma unroll
        for (int j = 0; j < 8; ++j)
            aW[g][j] = (_Float16)(sm * W_hh[R * 32 + 8 * kq + j]);
    }

    // ---- per-lane x-weights + bias for my 2 states (same batch) ----
    const int hid0 = 4 * g0 + kq;     // state 0 hid; state 1 = hid0+16
    float wx[2][4][3], bs[2][4];
#pragma unroll
    for (int s = 0; s < 2; ++s) {
#pragma unroll
        for (int r = 0; r < 4; ++r) {
            const int   R  = r * 32 + hid0 + 16 * s;
            const float sr = (r == 2) ? (-2.0f * LOG2E) : (-LOG2E);
            wx[s][r][0] = sr * W_ih[R * 3 + 0];
            wx[s][r][1] = sr * W_ih[R * 3 + 1];
            wx[s][r][2] = sr * W_ih[R * 3 + 2];
            bs[s][r]    = sr * (b_ih[R] + b_hh[R]);
        }
    }

    // zero h(0): 4*40 halves = 80 ints
    {
        int* hz = (int*)&hbuf[0][0];
        hz[lane] = 0;
        if (lane < 16) hz[64 + lane] = 0;
    }

    const float K2 = -2.0f * LOG2E;
    float c0 = 0.0f, c1 = 0.0f;
    const f32x4 z = {0.f, 0.f, 0.f, 0.f};
    const bool sb0 = (g0 & 1) != 0, sb1 = (g0 & 2) != 0;

    for (int tc = 0; tc < T_LEN; tc += CHUNK) {
        // ---- stage x chunk: 4 batches x 128 t x 3 comp = 1536 floats ----
        // coalesced scalar copy; (m,t,comp) map recomputed (amortized /128)
#pragma unroll
        for (int i = 0; i < 24; ++i) {
            const int flat = i * 64 + lane;          // 0..1535
            const int m = flat / 384;                // batch
            const int r = flat - m * 384;
            const int t = r / 3;
            const int comp = r - 3 * t;
            xbuf[m][t][comp] = x[(size_t)(tb + m) * (T_LEN * 3) + tc * 3 + r];
        }
        // same-wave DS order: writes precede reads, lgkmcnt enforced by compiler

        float4 xv = *(const float4*)&xbuf[nb][0][0];  // x(t=tc), [3] = garbage pad

#pragma unroll 2
        for (int tt = 0; tt < CHUNK; ++tt) {
            // issue h-read and next-x-read back-to-back (latencies overlap)
            const f16x8 bh  = *(const f16x8*)&hbuf[nb][8 * kq];
            const float4 xvN = *(const float4*)&xbuf[nb][(tt + 1) & (CHUNK - 1)][0];

            f32x4 ac[8];
#pragma unroll
            for (int g = 0; g < 8; ++g)
                ac[g] = __builtin_amdgcn_mfma_f32_16x16x32_f16(aW[g], bh, z, 0, 0, 0);

            // x-term + bias for both states (independent of h -> fills read wait)
            float xq0[4], xq1[4];
#pragma unroll
            for (int r = 0; r < 4; ++r) {
                xq0[r] = fmaf(wx[0][r][2], xv.z, fmaf(wx[0][r][1], xv.y, fmaf(wx[0][r][0], xv.x, bs[0][r])));
                xq1[r] = fmaf(wx[1][r][2], xv.z, fmaf(wx[1][r][1], xv.y, fmaf(wx[1][r][0], xv.x, bs[1][r])));
            }

            // two 1-of-4 selects (12 cndmask each)
            const f32x4 s01a = sb0 ? ac[1] : ac[0];
            const f32x4 s23a = sb0 ? ac[3] : ac[2];
            const f32x4 q0   = sb1 ? s23a : s01a;
            const f32x4 s01b = sb0 ? ac[5] : ac[4];
            const f32x4 s23b = sb0 ? ac[7] : ac[6];
            const f32x4 q1   = sb1 ? s23b : s01b;

            // ---- state 0 gate math (merged-reciprocal: 5 exp2 + 2 rcp) ----
            float h0, h1;
            {
                const float a0 = q0[0] + xq0[0], a1 = q0[1] + xq0[1];
                const float a2 = q0[2] + xq0[2], a3 = q0[3] + xq0[3];
                const float ei = ex2(a0), ef = ex2(a1), eg = ex2(a2), eo = ex2(a3);
                const float pi = 1.0f + ei, pf = 1.0f + ef, pg = 1.0f + eg;
                const float mg = 1.0f - eg;
                const float pp = pi * pg, qn = mg * pf;
                c0 = fmaf(c0, pp, qn) * rcp_(pf * pp);
                const float ec = ex2(c0 * K2);
                const float po = 1.0f + eo, pc = 1.0f + ec, mc = 1.0f - ec;
                h0 = mc * rcp_(po * pc);
            }
            // ---- state 1 (independent chain -> ILP with state 0) ----
            {
                const float a0 = q1[0] + xq1[0], a1 = q1[1] + xq1[1];
                const float a2 = q1[2] + xq1[2], a3 = q1[3] + xq1[3];
                const float ei = ex2(a0), ef = ex2(a1), eg = ex2(a2), eo = ex2(a3);
                const float pi = 1.0f + ei, pf = 1.0f + ef, pg = 1.0f + eg;
                const float mg = 1.0f - eg;
                const float pp = pi * pg, qn = mg * pf;
                c1 = fmaf(c1, pp, qn) * rcp_(pf * pp);
                const float ec = ex2(c1 * K2);
                const float po = 1.0f + eo, pc = 1.0f + ec, mc = 1.0f - ec;
                h1 = mc * rcp_(po * pc);
            }

            // same-wave h update: writes ordered after this step's bh read,
            // before next step's read (in-order DS pipe) -> no barrier needed
            hbuf[nb][hid0]      = (_Float16)h0;
            hbuf[nb][hid0 + 16] = (_Float16)h1;

            xv = xvN;
        }
    }

    // ---- epilogue: out[tb+m][cc] = b_fc[cc] + sum_k W_fc[cc][k]*h[m][k] ----
    if (lane < 12) {
        const int m = lane / 3, cc = lane % 3;
        float acc = b_fc[cc];
#pragma unroll
        for (int k = 0; k < 32; ++k)
            acc = fmaf(W_fc[cc * 32 + k], (float)hbuf[m][k], acc);
        out[(tb + m) * 3 + cc] = acc;
    }
}

extern "C" void kernel_launch(void* const* d_in, const int* in_sizes, int n_in,
                              void* d_out, int out_size, void* d_ws, size_t ws_size,
                              hipStream_t stream) {
    const float* x    = (const float*)d_in[0];
    const float* W_ih = (const float*)d_in[1];
    const float* W_hh = (const float*)d_in[2];
    const float* b_ih = (const float*)d_in[3];
    const float* b_hh = (const float*)d_in[4];
    const float* W_fc = (const float*)d_in[5];
    const float* b_fc = (const float*)d_in[6];
    float* out = (float*)d_out;

    dim3 grid(B_TOT / 4);    // 1024 single-wave blocks = 1 wave/SIMD exact
    dim3 block(64);
    lstm_sw<<<grid, block, 0, stream>>>(x, W_ih, W_hh, b_ih, b_hh, W_fc, b_fc, out);
}

// Round 13
// 184.032 us; speedup vs baseline: 1.3665x; 1.3665x over previous
//
#include <hip/hip_runtime.h>
#include <cstdint>

// B=4096, T=512, I=3, H=32, C=3
#define B_TOT 4096
#define T_LEN 512
#define CHUNK 256            // R13: fewer staging phases (was 128)
#define LOG2E 1.44269504088896340736f
#define HSTR  40             // hbuf inner stride in halves (80 B): 16B-aligned b128

typedef _Float16 f16x8 __attribute__((ext_vector_type(8)));
typedef _Float16 f16x4 __attribute__((ext_vector_type(4)));
typedef float    f32x4 __attribute__((ext_vector_type(4)));

__device__ __forceinline__ float ex2(float v)  { return __builtin_amdgcn_exp2f(v); }
__device__ __forceinline__ float rcp_(float v) { return __builtin_amdgcn_rcpf(v); }

// R8 structure (measured optimum of the family): 8-batch tile, 4 waves/block,
// 512 blocks -> 2 independent barrier domains per CU. Wave w owns hids
// [8w,8w+8) via TWO gate-MFMAs sharing one B fragment (cols = batch n&7, x2):
//   MFMA#1 rows m: gate=m&3, hid=8w+(m>>2); MFMA#2: hid=8w+4+(m>>2)
// Lane (n,kq) state: (batch n&7, hid 8w+kq+(n>=8?4:0)); 1-of-2 select.
// exp2 scales folded into A rows; bias via x-MFMA K-slot 3 (pad staged = 1.0).
// Merged-reciprocal gate math: 5 exp2 + 2 rcp per state per step.
// R13 deltas: (a) CHUNK=256 (halve staging phases); (b) x for two timesteps
// packed in one 16B LDS row -> one ds_read_b128 per TWO steps (was 2x b64),
// halving x-read LDS-pipe occupancy; inner loop iterates over step-pairs with
// the same one-barrier-per-step exchange.
__global__ __launch_bounds__(256, 2)
void lstm_pr(const float* __restrict__ x,
             const float* __restrict__ W_ih,
             const float* __restrict__ W_hh,
             const float* __restrict__ b_ih,
             const float* __restrict__ b_hh,
             const float* __restrict__ W_fc,
             const float* __restrict__ b_fc,
             float* __restrict__ out)
{
    __shared__ __align__(16) _Float16 hbuf[2][8][HSTR];       // 1.25 KB
    __shared__ __align__(16) _Float16 xbuf[CHUNK / 2][8][8];  // 16 KB: 2 steps/row

    const int tid  = threadIdx.x;
    const int wave = tid >> 6;        // 0..3
    const int lane = tid & 63;
    const int n    = lane & 15;
    const int kq   = lane >> 4;
    const int nb   = n & 7;           // batch column
    const int tb   = blockIdx.x * 8;

    // ---- A-fragment rows (m = n) for the two gate-MFMAs ----
    const int   gate_m = n & 3;
    const int   hl_m   = n >> 2;                       // 0..3
    const int   R1     = gate_m * 32 + 8 * wave + hl_m;
    const int   R2     = R1 + 4;
    const float sm     = (gate_m == 2) ? (-2.0f * LOG2E) : (-LOG2E);

    f16x8 aW1, aW2;
#pragma unroll
    for (int j = 0; j < 8; ++j) {
        aW1[j] = (_Float16)(sm * W_hh[R1 * 32 + 8 * kq + j]);
        aW2[j] = (_Float16)(sm * W_hh[R2 * 32 + 8 * kq + j]);
    }
    f16x8 a21 = {}, a22 = {};         // x-weights + bias (kq==0 lanes carry K 0..3)
    if (kq == 0) {
        a21[0] = (_Float16)(sm * W_ih[R1 * 3 + 0]);
        a21[1] = (_Float16)(sm * W_ih[R1 * 3 + 1]);
        a21[2] = (_Float16)(sm * W_ih[R1 * 3 + 2]);
        a21[3] = (_Float16)(sm * (b_ih[R1] + b_hh[R1]));
        a22[0] = (_Float16)(sm * W_ih[R2 * 3 + 0]);
        a22[1] = (_Float16)(sm * W_ih[R2 * 3 + 1]);
        a22[2] = (_Float16)(sm * W_ih[R2 * 3 + 2]);
        a22[3] = (_Float16)(sm * (b_ih[R2] + b_hh[R2]));
    }

    // my state: (batch nb, hid_s)
    const int hid_s = 8 * wave + kq + ((n >> 3) ? 4 : 0);

    // zero h(0) buffer (hbuf[0] = 8*HSTR halves = 160 ints)
    if (tid < 160) ((int*)&hbuf[0][0][0])[tid] = 0;

    const float K2 = -2.0f * LOG2E;
    float c = 0.0f;
    const f32x4 z = {0.f, 0.f, 0.f, 0.f};
    f32x4 accx1, accx2;   // x-contribution (incl. bias) for the CURRENT step

    const bool hi = (n >> 3) != 0;

    for (int tc = 0; tc < T_LEN; tc += CHUNK) {
        // ---- stage x chunk as fp16 pairs: row [t>>1][m] holds steps t,t+1;
        //      pad slot = 1.0 (bias trick) ----
#pragma unroll
        for (int s = 0; s < 8; ++s) {
            const int idx = tid + s * 256;          // 2048 (t,m) pairs
            const int tl = idx >> 3, m = idx & 7;
            const float* xp = x + ((size_t)(tb + m) * T_LEN + (tc + tl)) * 3;
            f16x4 v;
            v[0] = (_Float16)xp[0]; v[1] = (_Float16)xp[1];
            v[2] = (_Float16)xp[2]; v[3] = (_Float16)1.0f;
            *(f16x4*)&xbuf[tl >> 1][m][4 * (tl & 1)] = v;
        }
        __syncthreads();

        // first pair + accx for step 0
        f16x8 xp = *(const f16x8*)&xbuf[0][nb][0];
        {
            const f16x8 b2 = __builtin_shufflevector(xp, xp, 0, 1, 2, 3, 0, 1, 2, 3);
            accx1 = __builtin_amdgcn_mfma_f32_16x16x32_f16(a21, b2, z, 0, 0, 0);
            accx2 = __builtin_amdgcn_mfma_f32_16x16x32_f16(a22, b2, z, 0, 0, 0);
        }

        for (int t2 = 0; t2 < CHUNK / 2; ++t2) {
            // ================= even step (parity 0) =================
            {
                const f16x8 bh = *(const f16x8*)&hbuf[0][nb][8 * kq];
                const f32x4 ac1 = __builtin_amdgcn_mfma_f32_16x16x32_f16(aW1, bh, accx1, 0, 0, 0);
                const f32x4 ac2 = __builtin_amdgcn_mfma_f32_16x16x32_f16(aW2, bh, accx2, 0, 0, 0);

                const float a0 = hi ? ac2[0] : ac1[0];
                const float a1 = hi ? ac2[1] : ac1[1];
                const float a2 = hi ? ac2[2] : ac1[2];
                const float a3 = hi ? ac2[3] : ac1[3];

                const float ei = ex2(a0), ef = ex2(a1), eg = ex2(a2), eo = ex2(a3);
                const float pi = 1.0f + ei, pf = 1.0f + ef, pg = 1.0f + eg;
                const float mg = 1.0f - eg;
                const float pp = pi * pg, qn = mg * pf;
                c = fmaf(c, pp, qn) * rcp_(pf * pp);
                const float ec = ex2(c * K2);
                const float po = 1.0f + eo, pc = 1.0f + ec, mc = 1.0f - ec;
                const float h = mc * rcp_(po * pc);
                hbuf[1][nb][hid_s] = (_Float16)h;

                // accx for the odd step from the pair's hi half (data in regs)
                const f16x8 b2 = __builtin_shufflevector(xp, xp, 4, 5, 6, 7, 4, 5, 6, 7);
                accx1 = __builtin_amdgcn_mfma_f32_16x16x32_f16(a21, b2, z, 0, 0, 0);
                accx2 = __builtin_amdgcn_mfma_f32_16x16x32_f16(a22, b2, z, 0, 0, 0);
            }
            __syncthreads();

            // ================= odd step (parity 1) =================
            {
                // issue h-read and next pair's x-read back-to-back
                const f16x8 bh = *(const f16x8*)&hbuf[1][nb][8 * kq];
                const int t2n = (t2 + 1) & (CHUNK / 2 - 1);   // wrap -> dummy
                const f16x8 xpN = *(const f16x8*)&xbuf[t2n][nb][0];

                const f32x4 ac1 = __builtin_amdgcn_mfma_f32_16x16x32_f16(aW1, bh, accx1, 0, 0, 0);
                const f32x4 ac2 = __builtin_amdgcn_mfma_f32_16x16x32_f16(aW2, bh, accx2, 0, 0, 0);

                const float a0 = hi ? ac2[0] : ac1[0];
                const float a1 = hi ? ac2[1] : ac1[1];
                const float a2 = hi ? ac2[2] : ac1[2];
                const float a3 = hi ? ac2[3] : ac1[3];

                const float ei = ex2(a0), ef = ex2(a1), eg = ex2(a2), eo = ex2(a3);
                const float pi = 1.0f + ei, pf = 1.0f + ef, pg = 1.0f + eg;
                const float mg = 1.0f - eg;
                const float pp = pi * pg, qn = mg * pf;
                c = fmaf(c, pp, qn) * rcp_(pf * pp);
                const float ec = ex2(c * K2);
                const float po = 1.0f + eo, pc = 1.0f + ec, mc = 1.0f - ec;
                const float h = mc * rcp_(po * pc);
                hbuf[0][nb][hid_s] = (_Float16)h;

                // accx for next even step from xpN's lo half
                const f16x8 b2 = __builtin_shufflevector(xpN, xpN, 0, 1, 2, 3, 0, 1, 2, 3);
                accx1 = __builtin_amdgcn_mfma_f32_16x16x32_f16(a21, b2, z, 0, 0, 0);
                accx2 = __builtin_amdgcn_mfma_f32_16x16x32_f16(a22, b2, z, 0, 0, 0);
                xp = xpN;
            }
            __syncthreads();
        }
    }

    // ---- epilogue: out[tb+m][cc] = b_fc[cc] + sum_k W_fc[cc][k]*h[m][k] ----
    // final h (t=512) is in hbuf[0]; last loop barrier ordered it.
    if (tid < 24) {
        const int m = tid / 3, cc = tid % 3;
        float acc = b_fc[cc];
#pragma unroll
        for (int k = 0; k < 32; ++k)
            acc = fmaf(W_fc[cc * 32 + k], (float)hbuf[0][m][k], acc);
        out[(tb + m) * 3 + cc] = acc;
    }
}

extern "C" void kernel_launch(void* const* d_in, const int* in_sizes, int n_in,
                              void* d_out, int out_size, void* d_ws, size_t ws_size,
                              hipStream_t stream) {
    const float* x    = (const float*)d_in[0];
    const float* W_ih = (const float*)d_in[1];
    const float* W_hh = (const float*)d_in[2];
    const float* b_ih = (const float*)d_in[3];
    const float* b_hh = (const float*)d_in[4];
    const float* W_fc = (const float*)d_in[5];
    const float* b_fc = (const float*)d_in[6];
    float* out = (float*)d_out;

    dim3 grid(B_TOT / 8);    // 512 blocks -> 2 independent barrier domains per CU
    dim3 block(256);         // 4 waves, 8 hids/wave
    lstm_pr<<<grid, block, 0, stream>>>(x, W_ih, W_hh, b_ih, b_hh, W_fc, b_fc, out);
}